// Round 3
// baseline (65725.610 us; speedup 1.0000x reference)
//
#include <hip/hip_runtime.h>
#include <hip/hip_bf16.h>

#define SEQ 1024
#define HID 2048
#define BAT 128
#define VOC 256
#define NTOT 2304          // HID + VOC columns, concatenated
#define BN 48              // cols per block
#define NG 48              // col groups
#define MG 4               // row groups (128/32)
#define NB (NG * MG)       // 192 blocks -- all co-resident on 256 CUs
#define KC 128             // K chunk
#define NCHUNK (HID / KC)  // 16
#define APAD 136           // KC + 8 shorts: 272B row stride, conflict-benign
#define HBUF ((size_t)BAT * 2 * HID)   // one h buffer (hi+lo) in shorts

typedef __attribute__((ext_vector_type(8))) short short8;
typedef __attribute__((ext_vector_type(4))) float f32x4;

// --- bf16 split helpers (RN-even) ------------------------------------------
__device__ __forceinline__ unsigned short f2bf_rn(float v) {
    unsigned u = __float_as_uint(v);
    u += 0x7fffu + ((u >> 16) & 1u);
    return (unsigned short)(u >> 16);
}
__device__ __forceinline__ float bf2f(unsigned short s) {
    return __uint_as_float(((unsigned)s) << 16);
}

// ---------------------------------------------------------------------------
// prologue: Wg[ng][96][2048] bf16 — rows 0..47 hi, 48..95 lo of 48 cols.
// ---------------------------------------------------------------------------
__global__ __launch_bounds__(256) void wsplit(
    const float* __restrict__ Whh, const float* __restrict__ Wlin,
    short* __restrict__ Wg)
{
    const int n  = blockIdx.x;          // 0..2303
    const int ng = n / BN, rl = n % BN;
    short* dhi = Wg + ((size_t)ng * 96 + rl) * HID;
    short* dlo = dhi + (size_t)BN * HID;
    for (int k = threadIdx.x; k < HID; k += 256) {
        float v = (n < HID) ? Whh[(size_t)k * HID + n]
                            : Wlin[(size_t)k * VOC + (n - HID)];
        unsigned short h = f2bf_rn(v);
        dhi[k] = (short)h;
        dlo[k] = (short)f2bf_rn(v - bf2f(h));
    }
}

// ---------------------------------------------------------------------------
// init: split h0 into buffer 0 (group-major hi/lo) + zero the barrier counter
// ---------------------------------------------------------------------------
__global__ __launch_bounds__(256) void hsplit(
    const float* __restrict__ h0, short* __restrict__ hb,
    unsigned* __restrict__ cnt)
{
    if (blockIdx.x == 0 && threadIdx.x == 0) *cnt = 0u;
    for (int i = blockIdx.x * 256 + threadIdx.x; i < BAT * HID;
         i += gridDim.x * 256) {
        int row = i / HID, k = i % HID;
        int g = row >> 5, rl = row & 31;
        float v = h0[i];
        unsigned short h = f2bf_rn(v);
        short* base = hb + (size_t)g * 64 * HID;
        base[(size_t)rl * HID + k]        = (short)h;
        base[(size_t)(rl + 32) * HID + k] = (short)f2bf_rn(v - bf2f(h));
    }
}

// ---------------------------------------------------------------------------
// persistent kernel: all 1024 steps + final y pass, one grid barrier/step.
// ---------------------------------------------------------------------------
__global__ __launch_bounds__(384, 1) void rnn_all(
    short* __restrict__ hb,  const short* __restrict__ Wg,
    const float* __restrict__ Wxh, const float* __restrict__ bh,
    const float* __restrict__ blin, const int* __restrict__ x,
    float* __restrict__ out, unsigned* __restrict__ cnt)
{
    __shared__ short Alds[64 * APAD];   // rows 0..31 hi, 32..63 lo
    __shared__ short Wlds[96 * APAD];   // rows 0..47 hi, 48..95 lo

    const int tid = threadIdx.x;
    const int ng  = blockIdx.x;         // 0..47 (ng%8 -> XCD spread: 48%8==0)
    const int mg  = blockIdx.y;         // 0..3
    const short* Wgb = Wg + (size_t)ng * 96 * HID;

    const int lane = tid & 63;
    const int wv   = tid >> 6;          // 0..5
    const int mi   = wv & 1;
    const int ni   = wv >> 1;           // 0..2
    const int l15  = lane & 15;
    const int kl   = (lane >> 4) * 8;
    const int col  = ng * BN + ni * 16 + l15;     // 0..2303
    const int rl0  = mi * 16 + (lane >> 4) * 4;   // local row 0..31
    const bool pure_h = (ng * BN + BN <= HID);    // block has no y columns

    uint4 a0[3], a1[3], w0[4], w1[4];   // named double buffers (static idx)

    auto loadA = [&](const short* Ag, int c, uint4* a) {
        const int kb = c * KC;
        #pragma unroll
        for (int j = 0; j < 3; ++j) {
            int i = tid + j * 384;
            if (i < 1024) {
                int row = i >> 4, ko = (i & 15) * 8;
                a[j] = *reinterpret_cast<const uint4*>(&Ag[(size_t)row * HID + kb + ko]);
            }
        }
    };
    auto loadW = [&](int c, uint4* w) {
        const int kb = c * KC;
        #pragma unroll
        for (int j = 0; j < 4; ++j) {
            int i = tid + j * 384;
            int row = i >> 4, ko = (i & 15) * 8;
            w[j] = *reinterpret_cast<const uint4*>(&Wgb[(size_t)row * HID + kb + ko]);
        }
    };
    auto storeA = [&](uint4* a) {
        #pragma unroll
        for (int j = 0; j < 3; ++j) {
            int i = tid + j * 384;
            if (i < 1024) {
                int row = i >> 4, ko = (i & 15) * 8;
                *reinterpret_cast<uint4*>(&Alds[row * APAD + ko]) = a[j];
            }
        }
    };
    auto storeW = [&](uint4* w) {
        #pragma unroll
        for (int j = 0; j < 4; ++j) {
            int i = tid + j * 384;
            int row = i >> 4, ko = (i & 15) * 8;
            *reinterpret_cast<uint4*>(&Wlds[row * APAD + ko]) = w[j];
        }
    };

    const short* Abase = &Alds[(mi * 16 + l15) * APAD + kl];
    const short* Bbase = &Wlds[(ni * 16 + l15) * APAD + kl];
    auto mfma_chunk = [&](f32x4& acc) {
        #pragma unroll
        for (int kk = 0; kk < 4; ++kk) {
            short8 ah = *reinterpret_cast<const short8*>(&Abase[kk * 32]);
            short8 al = *reinterpret_cast<const short8*>(&Abase[32 * APAD + kk * 32]);
            short8 bh = *reinterpret_cast<const short8*>(&Bbase[kk * 32]);
            short8 bl = *reinterpret_cast<const short8*>(&Bbase[48 * APAD + kk * 32]);
            acc = __builtin_amdgcn_mfma_f32_16x16x32_bf16(ah, bh, acc, 0, 0, 0);
            acc = __builtin_amdgcn_mfma_f32_16x16x32_bf16(ah, bl, acc, 0, 0, 0);
            acc = __builtin_amdgcn_mfma_f32_16x16x32_bf16(al, bh, acc, 0, 0, 0);
        }
    };

    // W chunks 0,1 for the first iteration (W immutable -> barrier-safe)
    loadW(0, w0); loadW(1, w1);

    for (int t = 0; t <= SEQ; ++t) {
        const short* hprev = hb + (size_t)(t % 3) * HBUF;
        short*       hnext = hb + (size_t)((t + 1) % 3) * HBUF;
        const short* Ag    = hprev + (size_t)mg * 64 * HID;
        const bool active  = !(pure_h && t == SEQ);   // block-uniform

        if (active) {
            // early x / Wxh gather (immutable data -> hides under K-loop)
            const bool hlane = (col < HID) && (t < SEQ);
            int xv[4]; float wx[4];
            if (hlane) {
                #pragma unroll
                for (int r = 0; r < 4; ++r)
                    xv[r] = x[(size_t)(mg * 32 + rl0 + r) * SEQ + t];
                #pragma unroll
                for (int r = 0; r < 4; ++r)
                    wx[r] = Wxh[(size_t)xv[r] * HID + col];
            }

            loadA(Ag, 0, a0); loadA(Ag, 1, a1);
            f32x4 acc = {0.f, 0.f, 0.f, 0.f};

            for (int c = 0; c < NCHUNK; c += 2) {
                __syncthreads();
                storeA(a0); storeW(w0);
                __syncthreads();
                if (c + 2 < NCHUNK) { loadA(Ag, c + 2, a0); loadW(c + 2, w0); }
                mfma_chunk(acc);

                __syncthreads();
                storeA(a1); storeW(w1);
                __syncthreads();
                if (c + 3 < NCHUNK) { loadA(Ag, c + 3, a1); loadW(c + 3, w1); }
                mfma_chunk(acc);
            }

            // prefetch W chunks 0,1 for next step; overlaps barrier wait
            if (t < SEQ) { loadW(0, w0); loadW(1, w1); }

            if (hlane) {
                short* hn = hnext + (size_t)mg * 64 * HID;
                #pragma unroll
                for (int r = 0; r < 4; ++r) {
                    const int rl   = rl0 + r;
                    const int grow = mg * 32 + rl;
                    float th = tanhf(acc[r] + wx[r] + bh[col]);
                    unsigned short hi = f2bf_rn(th);
                    hn[(size_t)rl * HID + col]        = (short)hi;
                    hn[(size_t)(rl + 32) * HID + col] = (short)f2bf_rn(th - bf2f(hi));
                    if (t == SEQ - 1)
                        out[(size_t)BAT * SEQ * VOC + (size_t)grow * HID + col] = th;
                }
            } else if (col >= HID && t > 0) {
                const int vc = col - HID;
                const float bl = blin[vc];
                #pragma unroll
                for (int r = 0; r < 4; ++r) {
                    const int grow = mg * 32 + rl0 + r;
                    out[((size_t)grow * SEQ + (t - 1)) * VOC + vc] = acc[r] + bl;
                }
            }
        }

        // ---- grid barrier (skip after final pass) --------------------------
        if (t < SEQ) {
            __syncthreads();                    // drains this block's stores
            if (tid == 0) {
                __builtin_amdgcn_fence(__ATOMIC_RELEASE, "agent");   // wb L2
                __hip_atomic_fetch_add(cnt, 1u, __ATOMIC_RELAXED,
                                       __HIP_MEMORY_SCOPE_AGENT);
                const unsigned target = (unsigned)NB * (unsigned)(t + 1);
                int spins = 0;
                while (__hip_atomic_load(cnt, __ATOMIC_RELAXED,
                                         __HIP_MEMORY_SCOPE_AGENT) < target) {
                    __builtin_amdgcn_s_sleep(2);
                    if (++spins > (1 << 22)) break;   // safety: no infinite hang
                }
                __builtin_amdgcn_fence(__ATOMIC_ACQUIRE, "agent");   // inv L1/L2
            }
            __syncthreads();
        }
    }
}

// ---------------------------------------------------------------------------
extern "C" void kernel_launch(void* const* d_in, const int* in_sizes, int n_in,
                              void* d_out, int out_size, void* d_ws, size_t ws_size,
                              hipStream_t stream) {
    const int*   x    = (const int*)  d_in[0];
    const float* h0   = (const float*)d_in[1];
    const float* Wxh  = (const float*)d_in[2];
    const float* Whh  = (const float*)d_in[3];
    const float* bh   = (const float*)d_in[4];
    const float* Wlin = (const float*)d_in[5];
    const float* blin = (const float*)d_in[6];
    float* out = (float*)d_out;

    // ws layout (shorts): Wg[48*96*2048] | hb[3 * HBUF] | cnt
    short* Wg  = (short*)d_ws;
    short* hb  = Wg + (size_t)NG * 96 * HID;
    unsigned* cnt = (unsigned*)(hb + 3 * HBUF);

    wsplit<<<dim3(NTOT), 256, 0, stream>>>(Whh, Wlin, Wg);
    hsplit<<<dim3(256), 256, 0, stream>>>(h0, hb, cnt);
    rnn_all<<<dim3(NG, MG), 384, 0, stream>>>(hb, Wg, Wxh, bh, blin, x, out, cnt);
}

// Round 5
// 23775.047 us; speedup vs baseline: 2.7645x; 2.7645x over previous
//
#include <hip/hip_runtime.h>
#include <hip/hip_bf16.h>

#define SEQ 1024
#define HID 2048
#define BAT 128
#define VOC 256
#define NTOT 2304          // HID + VOC columns, concatenated
#define BN 48              // cols per block
#define NG 48              // col groups
#define MG 4               // row groups (128/32)
#define NB (NG * MG)       // 192 blocks, <=256 CUs -> all co-resident
#define KC 128             // K chunk
#define NCHUNK (HID / KC)  // 16
#define APAD 136           // row stride in shorts (272B)

typedef __attribute__((ext_vector_type(4))) unsigned u32x4;
typedef __attribute__((ext_vector_type(2))) unsigned u32x2;
typedef __attribute__((ext_vector_type(8))) short short8;
typedef __attribute__((ext_vector_type(4))) float f32x4;

// counted vmem wait + scheduler fence (rule #18)
#define WAITVM(N) do { asm volatile("s_waitcnt vmcnt(" #N ")" ::: "memory"); \
                       __builtin_amdgcn_sched_barrier(0); } while (0)
// block barrier with LDS drain + compiler memory fence (== __syncthreads power)
#define BARRIER() asm volatile("s_waitcnt lgkmcnt(0)\n\ts_barrier" ::: "memory")

// --- asm memory ops ---------------------------------------------------------
__device__ __forceinline__ u32x4 ld16(const void* p) {          // cached (L1/L2)
    u32x4 r; asm volatile("global_load_dwordx4 %0, %1, off" : "=v"(r) : "v"(p)); return r;
}
__device__ __forceinline__ u32x4 ld16_coh(const void* p) {      // bypass -> LLC
    u32x4 r; asm volatile("global_load_dwordx4 %0, %1, off sc0 sc1" : "=v"(r) : "v"(p)); return r;
}
__device__ __forceinline__ int ld4i(const void* p) {
    int r; asm volatile("global_load_dword %0, %1, off" : "=v"(r) : "v"(p)); return r;
}
__device__ __forceinline__ float ld4f(const void* p) {
    float r; asm volatile("global_load_dword %0, %1, off" : "=v"(r) : "v"(p)); return r;
}
__device__ __forceinline__ unsigned ld4_coh(const void* p) {    // fresh LLC read
    unsigned r;
    asm volatile("global_load_dword %0, %1, off sc0 sc1\n\ts_waitcnt vmcnt(0)"
                 : "=v"(r) : "v"(p) : "memory");
    return r;
}
// h-store: atomic swap (no return) -> completes AT the LLC coherence point,
// so vmcnt drain == cross-XCD visibility (no posted-write window).
__device__ __forceinline__ void st4_llc(void* p, unsigned v) {
    asm volatile("global_atomic_swap %0, %1, off" :: "v"(p), "v"(v) : "memory");
}

// --- bf16 split helpers (RN-even) ------------------------------------------
__device__ __forceinline__ unsigned short f2bf_rn(float v) {
    unsigned u = __float_as_uint(v);
    u += 0x7fffu + ((u >> 16) & 1u);
    return (unsigned short)(u >> 16);
}
__device__ __forceinline__ float bf2f(unsigned short s) {
    return __uint_as_float(((unsigned)s) << 16);
}

// ---------------------------------------------------------------------------
// prologue: Wg[ng][96][2048] bf16 — rows 0..47 hi, 48..95 lo of 48 cols.
// ---------------------------------------------------------------------------
__global__ __launch_bounds__(256) void wsplit(
    const float* __restrict__ Whh, const float* __restrict__ Wlin,
    short* __restrict__ Wg)
{
    const int n  = blockIdx.x;          // 0..2303
    const int ng = n / BN, rl = n % BN;
    short* dhi = Wg + ((size_t)ng * 96 + rl) * HID;
    short* dlo = dhi + (size_t)BN * HID;
    for (int k = threadIdx.x; k < HID; k += 256) {
        float v = (n < HID) ? Whh[(size_t)k * HID + n]
                            : Wlin[(size_t)k * VOC + (n - HID)];
        unsigned short h = f2bf_rn(v);
        dhi[k] = (short)h;
        dlo[k] = (short)f2bf_rn(v - bf2f(h));
    }
}

// ---------------------------------------------------------------------------
// init: h0 -> packed u32 (hi<<16|lo), row-major [128][2048]; zero barrier cnt
// ---------------------------------------------------------------------------
__global__ __launch_bounds__(256) void hsplit(
    const float* __restrict__ h0, unsigned* __restrict__ hb,
    unsigned* __restrict__ cnt)
{
    if (blockIdx.x == 0 && threadIdx.x == 0)
        __hip_atomic_store(cnt, 0u, __ATOMIC_RELAXED, __HIP_MEMORY_SCOPE_SYSTEM);
    for (int i = blockIdx.x * 256 + threadIdx.x; i < BAT * HID;
         i += gridDim.x * 256) {
        float v = h0[i];
        unsigned short h = f2bf_rn(v);
        unsigned short l = f2bf_rn(v - bf2f(h));
        hb[i] = ((unsigned)h << 16) | l;
    }
}

// ---------------------------------------------------------------------------
// persistent kernel: 1024 steps + final y pass; no cache-wide fences.
// h exchange: atomic-swap stores -> LLC, sc0sc1 loads <- LLC.
// W/Wxh/x/bh stay L2-resident across all steps.
// ---------------------------------------------------------------------------
__global__ __launch_bounds__(384, 1) void rnn_all(
    unsigned* __restrict__ hb, const short* __restrict__ Wg,
    const float* __restrict__ Wxh, const float* __restrict__ bh,
    const float* __restrict__ blin, const int* __restrict__ x,
    float* __restrict__ out, unsigned* __restrict__ cnt)
{
    __shared__ short Alds[2][64 * APAD];   // per buf: rows 0..31 hi, 32..63 lo
    __shared__ short Wlds[2][96 * APAD];   // per buf: rows 0..47 hi, 48..95 lo

    const int tid = threadIdx.x;
    const int ng  = blockIdx.x;            // 0..47 (round-robin -> XCD spread)
    const int mg  = blockIdx.y;            // 0..3
    const short* Wgb = Wg + (size_t)ng * 96 * HID;

    const int lane = tid & 63;
    const int wv   = tid >> 6;             // 0..5
    const int mi   = wv & 1;
    const int ni   = wv >> 1;              // 0..2
    const int l15  = lane & 15;
    const int kl   = (lane >> 4) * 8;
    const int col  = ng * BN + ni * 16 + l15;     // 0..2303 (wave-uniform side)
    const int rl0  = mi * 16 + (lane >> 4) * 4;   // local row 0..31
    const bool pure_h = (ng * BN + BN <= HID);

    float bhv = 0.f, blv = 0.f;
    if (col < HID) bhv = bh[col]; else blv = blin[col - HID];

    u32x4 a0[3], a1[3], w0[4], w1[4];      // named double buffers (static idx)

    auto issueA = [&](const unsigned* Hp, int c, u32x4* a) {
        const unsigned* base = Hp + (size_t)mg * 32 * HID + c * KC;
        #pragma unroll
        for (int j = 0; j < 3; ++j) {
            int g  = tid + j * 384;
            int gg = g & 1023;             // dup addr for g>=1024: uniform vmcnt
            int row = gg >> 5, kq = (gg & 31) * 4;
            a[j] = ld16_coh(base + (size_t)row * HID + kq);
        }
    };
    auto issueW = [&](int c, u32x4* w) {
        const short* base = Wgb + c * KC;
        #pragma unroll
        for (int j = 0; j < 4; ++j) {
            int g = tid + j * 384;
            int row = g >> 4, ko = (g & 15) * 8;
            w[j] = ld16(base + (size_t)row * HID + ko);
        }
    };
    auto stA = [&](int p, u32x4* a) {      // unpack packed u32 -> hi/lo planes
        short* L = &Alds[p][0];
        #pragma unroll
        for (int j = 0; j < 3; ++j) {
            int g = tid + j * 384;
            if (g < 1024) {
                int row = g >> 5, kq = (g & 31) * 4;
                u32x4 v = a[j];
                unsigned h01 = (v[0] >> 16)     | (v[1] & 0xFFFF0000u);
                unsigned h23 = (v[2] >> 16)     | (v[3] & 0xFFFF0000u);
                unsigned l01 = (v[0] & 0xFFFFu) | (v[1] << 16);
                unsigned l23 = (v[2] & 0xFFFFu) | (v[3] << 16);
                *reinterpret_cast<u32x2*>(&L[row * APAD + kq])        = (u32x2){h01, h23};
                *reinterpret_cast<u32x2*>(&L[(row + 32) * APAD + kq]) = (u32x2){l01, l23};
            }
        }
    };
    auto stW = [&](int p, u32x4* w) {
        short* L = &Wlds[p][0];
        #pragma unroll
        for (int j = 0; j < 4; ++j) {
            int g = tid + j * 384;
            int row = g >> 4, ko = (g & 15) * 8;
            *reinterpret_cast<u32x4*>(&L[row * APAD + ko]) = w[j];
        }
    };
    auto mf = [&](int p, f32x4& acc) {
        const short* Ab = &Alds[p][(mi * 16 + l15) * APAD + kl];
        const short* Bb = &Wlds[p][(ni * 16 + l15) * APAD + kl];
        #pragma unroll
        for (int kk = 0; kk < 4; ++kk) {
            short8 ah = *reinterpret_cast<const short8*>(&Ab[kk * 32]);
            short8 al = *reinterpret_cast<const short8*>(&Ab[32 * APAD + kk * 32]);
            short8 bh = *reinterpret_cast<const short8*>(&Bb[kk * 32]);
            short8 bl = *reinterpret_cast<const short8*>(&Bb[48 * APAD + kk * 32]);
            acc = __builtin_amdgcn_mfma_f32_16x16x32_bf16(ah, bh, acc, 0, 0, 0);
            acc = __builtin_amdgcn_mfma_f32_16x16x32_bf16(ah, bl, acc, 0, 0, 0);
            acc = __builtin_amdgcn_mfma_f32_16x16x32_bf16(al, bh, acc, 0, 0, 0);
        }
    };

    issueW(0, w0); issueW(1, w1);          // W chunks 0,1 for t=0

    for (int t = 0; t <= SEQ; ++t) {
        const unsigned* Hp = hb + (size_t)(t % 3) * BAT * HID;
        unsigned*       Hn = hb + (size_t)((t + 1) % 3) * BAT * HID;
        const bool active = !(pure_h && t == SEQ);   // block-uniform

        if (active) {
            const bool hlane = (col < HID) && (t < SEQ);  // wave-uniform
            int xv[4]; float wx[4];
            if (hlane) {
                #pragma unroll
                for (int r = 0; r < 4; ++r)
                    xv[r] = ld4i(&x[(size_t)(mg * 32 + rl0 + r) * SEQ + t]);
                WAITVM(0);
                #pragma unroll
                for (int r = 0; r < 4; ++r)
                    wx[r] = ld4f(&Wxh[(size_t)xv[r] * HID + col]);
            }

            issueA(Hp, 0, a0); issueA(Hp, 1, a1);
            f32x4 acc = {0.f, 0.f, 0.f, 0.f};

            #pragma unroll
            for (int c = 0; c < NCHUNK; ++c) {
                u32x4* ab = (c & 1) ? a1 : a0;
                u32x4* wb = (c & 1) ? w1 : w0;
                if (c == 0)               { WAITVM(3); }  // A0 ready (a1 flying)
                else if (c == NCHUNK - 1) { WAITVM(0); }  // tail: drain all
                else                      { WAITVM(7); }  // chunk c's 7 done
                stA(c & 1, ab); stW(c & 1, wb);
                BARRIER();                                // lgkm drain + fence
                if (c + 2 < NCHUNK) { issueA(Hp, c + 2, ab); issueW(c + 2, wb); }
                mf(c & 1, acc);
            }

            if (hlane) {
                #pragma unroll
                for (int r = 0; r < 4; ++r) {
                    const int rl = rl0 + r, grow = mg * 32 + rl;
                    float th = tanhf(acc[r] + wx[r] + bhv);
                    unsigned short hi = f2bf_rn(th);
                    unsigned short lo = f2bf_rn(th - bf2f(hi));
                    st4_llc(Hn + (size_t)grow * HID + col,
                            ((unsigned)hi << 16) | lo);
                    if (t == SEQ - 1)
                        __builtin_nontemporal_store(
                            th, &out[(size_t)BAT * SEQ * VOC + (size_t)grow * HID + col]);
                }
            } else if (col >= HID && t > 0) {
                const int vc = col - HID;
                #pragma unroll
                for (int r = 0; r < 4; ++r) {
                    const int grow = mg * 32 + rl0 + r;
                    __builtin_nontemporal_store(
                        acc[r] + blv, &out[((size_t)grow * SEQ + (t - 1)) * VOC + vc]);
                }
            }

            issueW(0, w0); issueW(1, w1);  // next-step W prefetch (stays in flight)
        }

        // ---- grid barrier: swaps ack'd at LLC + counter, no cache fences ---
        if (t < SEQ) {
            WAITVM(8);                     // h-swaps at LLC; 8 W loads fly on
            BARRIER();
            if (tid == 0) {
                __hip_atomic_fetch_add(cnt, 1u, __ATOMIC_RELAXED,
                                       __HIP_MEMORY_SCOPE_AGENT);
                const unsigned target = (unsigned)NB * (unsigned)(t + 1);
                int spins = 0;
                while (ld4_coh(cnt) < target) {
                    __builtin_amdgcn_s_sleep(1);
                    if (++spins > (1 << 22)) break;   // safety valve
                }
            }
            BARRIER();
        }
    }
}

// ---------------------------------------------------------------------------
extern "C" void kernel_launch(void* const* d_in, const int* in_sizes, int n_in,
                              void* d_out, int out_size, void* d_ws, size_t ws_size,
                              hipStream_t stream) {
    const int*   x    = (const int*)  d_in[0];
    const float* h0   = (const float*)d_in[1];
    const float* Wxh  = (const float*)d_in[2];
    const float* Whh  = (const float*)d_in[3];
    const float* bh   = (const float*)d_in[4];
    const float* Wlin = (const float*)d_in[5];
    const float* blin = (const float*)d_in[6];
    float* out = (float*)d_out;

    // ws: Wg shorts [48*96*2048] | hb u32 [3*128*2048] | cnt u32
    short*    Wg  = (short*)d_ws;
    unsigned* hb  = (unsigned*)(Wg + (size_t)NG * 96 * HID);
    unsigned* cnt = hb + (size_t)3 * BAT * HID;

    wsplit<<<dim3(NTOT), 256, 0, stream>>>(Whh, Wlin, Wg);
    hsplit<<<dim3(256), 256, 0, stream>>>(h0, hb, cnt);
    rnn_all<<<dim3(NG, MG), 384, 0, stream>>>(hb, Wg, Wxh, bh, blin, x, out, cnt);
}